// Round 12
// baseline (339.927 us; speedup 1.0000x reference)
//
#include <hip/hip_runtime.h>
#include <hip/hip_bf16.h>
#include <cmath>

// ---------------------------------------------------------------------------
// HeavyEncoderLayer, MI355X. R12:
//  - k2: launch_bounds(256,4). At (256,2) occupancy was 2 blocks/CU -> 750
//    blocks ran in TWO rounds (512+238, second half-empty). LDS 40448 allows
//    4 blocks/CU and VGPR=80 allows 6 waves/SIMD -> single-round residency.
//  - k3/k5: reverted to R8-proven versions (R11's TLP variants regressed:
//    8-node k3 doubled MFMA+B-traffic on zero padding).
//  - memset folded into k_prep (zero-fill section) -> one fewer dispatch.
// ---------------------------------------------------------------------------

#define N_NODES 8000
#define N_EDGES 24000

#define INV_SQRT3f 0.57735026918962576f
#define PW_MSG0f 0.10206207261596575f   /* sqrt(1/96) */
#define PW1f     0.10206207261596575f   /* PW_MSG1*INV_SQRT3 == sqrt(1/96) */
#define PW_G01f  0.022097086912079608f  /* sqrt(1/2048) */
#define PW_G2f   0.034232659844072866f  /* sqrt(3/2560) */
#define PW_H0f   0.031008683647302115f  /* sqrt(1/1040) */
#define PW_H1f   0.30618621784789724f   /* sqrt(3/32) */
#define RSQRT128f 0.08838834764831845f
#define RSQRT32f  0.17677669529663687f

typedef short short8 __attribute__((ext_vector_type(8)));
typedef short short4v __attribute__((ext_vector_type(4)));
typedef float f32x4 __attribute__((ext_vector_type(4)));

__device__ inline short f32_to_bf16_bits(float v) {
  unsigned int b = __builtin_bit_cast(unsigned int, v);
  b += 0x7fffu + ((b >> 16) & 1u);        // RNE (no NaN inputs here)
  return (short)(b >> 16);
}

// ---------------- unified prep: W2 swizzle, Wg tables, k1, zero-fill -------
// b <  576 : W2 -> w2s swizzled fragments
// b < 1344 : gate tables, fragment order
// b < 1413 : Wd / WL0 / WL1 transposes
// b < 4413 : k1 edge MLP -> bf16
// b < 6171 : zero nm/sums/cnt (replaces hipMemsetAsync dispatch)
__global__ __launch_bounds__(256) void k_prep(const float* __restrict__ W2,
                                              const float* __restrict__ Wg000,
                                              const float* __restrict__ Wg110,
                                              const float* __restrict__ Wg001,
                                              const float* __restrict__ Wg111,
                                              const float* __restrict__ Wg012,
                                              const float* __restrict__ Wg102,
                                              const float* __restrict__ Wd,
                                              const float* __restrict__ WL0,
                                              const float* __restrict__ WL1,
                                              const float* __restrict__ ea,
                                              const float* __restrict__ W1,
                                              short* __restrict__ w2s,
                                              short* __restrict__ bt,
                                              float* __restrict__ wdt,
                                              float* __restrict__ wl0t,
                                              float* __restrict__ wl1t,
                                              short* __restrict__ hbf,
                                              float* __restrict__ zero_base,
                                              float cst_silu) {
  const int b = blockIdx.x, tid = threadIdx.x;
  if (b < 576) {                         // W2 -> w2s (swizzled)
    __shared__ float tile[32][33];
    const int kt = b & 3, ct = b >> 2;
    const int k0 = kt*32, c0 = ct*32;
    const int tx = tid & 31, ty = tid >> 5;   // 32 x 8
#pragma unroll
    for (int i = 0; i < 4; ++i) {
      int r = ty + i*8;
      tile[r][tx] = W2[(k0+r)*4608 + c0 + tx];
    }
    __syncthreads();
#pragma unroll
    for (int i = 0; i < 4; ++i) {
      int r = ty + i*8;
      const int c = c0 + r, k = k0 + tx;
      const int id = (c < 1024) ? (c >> 4)
                   : (c < 4096) ? ((c + 512) >> 4) : ((c - 3072) >> 4);
      const int nn = c & 15, ks = k >> 5, quad = (k >> 3) & 3, jj = k & 7;
      w2s[id*2048 + ks*512 + (quad*16 + nn)*8 + jj] = f32_to_bf16_bits(tile[tx][r]);
    }
  } else if (b < 1344) {                 // gate tables, fragment order
    int i = (b - 576) * 256 + tid;       // < 196608 exact
    float v;
    if (i < 16384) {                     // b000s
      int u = i >> 10, r = i & 1023;
      int ks = r >> 9, lane = (r >> 3) & 63, j = r & 7;
      int k = ks*32 + (lane >> 4)*8 + j, nn = lane & 15;
      v = Wg000[u*1024 + k*16 + nn];
    } else if (i < 49152) {              // b001s
      int o = i - 16384;
      int tau = o >> 10, r = o & 1023;
      int u = tau >> 1, wh = tau & 1;
      int ks = r >> 9, lane = (r >> 3) & 63, j = r & 7;
      int k = ks*32 + (lane >> 4)*8 + j, nn = lane & 15;
      v = Wg001[u*2048 + k*32 + wh*16 + nn];
    } else if (i < 65536) {              // b110s
      int o = i - 49152;
      int u = o >> 9, r = o & 511;
      int lane = r >> 3, j = r & 7;
      int k = (lane >> 4)*8 + j, nn = lane & 15;
      v = INV_SQRT3f * Wg110[u*512 + k*16 + nn];
    } else if (i < 98304) {              // b111s
      int o = i - 65536;
      int tau = o >> 9, r = o & 511;
      int u = tau >> 1, wh = tau & 1;
      int lane = r >> 3, j = r & 7;
      int k = (lane >> 4)*8 + j, nn = lane & 15;
      v = INV_SQRT3f * Wg111[u*1024 + k*32 + wh*16 + nn];
    } else if (i < 131072) {             // b012s (k=u, padded)
      int o = i - 98304;
      int tau = o >> 9, r = o & 511;
      int vv = tau >> 1, wh = tau & 1;
      int lane = r >> 3, j = r & 7;
      int k = (lane >> 4)*8 + j, nn = lane & 15;
      v = (k < 16) ? Wg012[k*1024 + vv*32 + wh*16 + nn] : 0.f;
    } else {                             // b102s
      int o = i - 131072;
      int tau = o >> 10, r = o & 1023;
      int u = tau >> 1, wh = tau & 1;
      int ks = r >> 9, lane = (r >> 3) & 63, j = r & 7;
      int k = ks*32 + (lane >> 4)*8 + j, nn = lane & 15;
      v = Wg102[u*2048 + k*32 + wh*16 + nn];
    }
    bt[i] = f32_to_bf16_bits(v);
  } else if (b < 1413) {                 // small f32 transposes
    int i = (b - 1344) * 256 + tid;      // < 17664 exact
    if (i < 16384) {                     // Wdt[k][uv] = Wd[uv*16+k]
      int k = i >> 10, uv = i & 1023;
      wdt[i] = Wd[uv*16 + k];
    } else if (i < 16640) {              // WL0t[j][v]
      int j = i - 16384; int jj = j >> 4, v = j & 15;
      wl0t[j] = WL0[v*16 + jj];
    } else if (i < 17664) {              // WL1t[w][u]
      int j = i - 16640; int w = j >> 5, u = j & 31;
      wl1t[j] = WL1[u*32 + w];
    }
  } else if (b < 4413) {                 // k1: edge MLP -> bf16 (x4 vec)
    int idx = (b - 1413) * 256 + tid;    // e*32 + q, 768000 exact
    int e = idx >> 5, q = idx & 31;
    const float a0 = ea[e*4+0], a1 = ea[e*4+1], a2 = ea[e*4+2], a3 = ea[e*4+3];
    const float4 w0 = *(const float4*)&W1[q*4];
    const float4 w1 = *(const float4*)&W1[128 + q*4];
    const float4 w2 = *(const float4*)&W1[256 + q*4];
    const float4 w3 = *(const float4*)&W1[384 + q*4];
    float s[4] = {0.5f*(a0*w0.x + a1*w1.x + a2*w2.x + a3*w3.x),
                  0.5f*(a0*w0.y + a1*w1.y + a2*w2.y + a3*w3.y),
                  0.5f*(a0*w0.z + a1*w1.z + a2*w2.z + a3*w3.z),
                  0.5f*(a0*w0.w + a1*w1.w + a2*w2.w + a3*w3.w)};
    short4v o;
#pragma unroll
    for (int i = 0; i < 4; ++i) {
      float sg = 1.f / (1.f + expf(-s[i]));
      o[i] = f32_to_bf16_bits(cst_silu * s[i] * sg * RSQRT128f);
    }
    *(short4v*)&hbf[idx*4] = o;
  } else {                               // zero nm/sums/cnt (1,800,000 floats)
    int i = (b - 4413) * 256 + tid;      // float4 index
    if (i < 450000) {
      f32x4 zz = {0.f,0.f,0.f,0.f};
      *(f32x4*)&zero_base[i*4] = zz;
    }
  }
}

// ---------------- K2: MFMA edge GEMM (R8 config, 4 blocks/CU) --------------
__global__ __launch_bounds__(256, 4) void k2_edge_msg(
    const float* __restrict__ x, const float* __restrict__ ea,
    const short* __restrict__ w2s, const short* __restrict__ hbf,
    const int* __restrict__ ei, float* __restrict__ nm) {
  __shared__ float msg_s[32][116];     // pad 116: flush conflicts 4->2-way
  __shared__ float x0pt[64][32];       // [u][e] PW1*xs0
  __shared__ float z2wt[32][32];       // [u][e] PW0*inv3*(xs1[u].a1)
  __shared__ float x1wt[32][32][3];    // [u][e][m] PW1*a0*xs1[u][m]
  __shared__ float a_s[32][4];
  __shared__ int srcs_s[32], dsts_s[32];

  const int tid = threadIdx.x;
  const int e0 = blockIdx.x * 32;

  if (tid < 32) { srcs_s[tid] = ei[e0+tid]; dsts_s[tid] = ei[N_EDGES + e0 + tid]; }
  if (tid < 128) a_s[tid>>2][tid&3] = ea[e0*4 + tid];
  for (int i = tid; i < 32*116; i += 256) (&msg_s[0][0])[i] = 0.f;
  __syncthreads();

  for (int i = tid; i < 2048; i += 256) {      // coalesced x0 gather
    int e = i >> 6, u = i & 63;
    x0pt[u][e] = PW1f * x[srcs_s[e]*160 + u];
  }
  for (int i = tid; i < 1024; i += 256) {
    int e = i >> 5, u = i & 31;
    const float* xp = &x[srcs_s[e]*160 + 64 + u*3];
    float m0v = xp[0], m1v = xp[1], m2v = xp[2];
    float a0 = a_s[e][0];
    z2wt[u][e] = PW_MSG0f * INV_SQRT3f *
                 (m0v*a_s[e][1] + m1v*a_s[e][2] + m2v*a_s[e][3]);
    x1wt[u][e][0] = PW1f * a0 * m0v;
    x1wt[u][e][1] = PW1f * a0 * m1v;
    x1wt[u][e][2] = PW1f * a0 * m2v;
  }
  __syncthreads();

  const int lane = tid & 63, wv = tid >> 6;
  const int quad = lane >> 4, nn = lane & 15;
  const int eq = quad * 4;

  short8 af[2][4];
#pragma unroll
  for (int t = 0; t < 2; ++t)
#pragma unroll
    for (int ks = 0; ks < 4; ++ks)
      af[t][ks] = *(const short8*)&hbf[(e0 + t*16 + nn)*128 + ks*32 + quad*8];

  float p000[2][4] = {};      // s000: x0pt fold (x a0 at flush)
  float p0[2][4] = {};        // s110: z2wt fold
  float p011[2][4] = {};      // s011: x0pt fold (x a1[m] at flush)
  float p101[2][4][3] = {};   // s101: x1wt fold

  short8 B0[4], B1[4], B2[4];
  auto loadB = [&](short8* B, int id) {
    const int idc = (id < 287) ? id : 287;     // clamp tail prefetch
    const short* p = w2s + idc*2048 + lane*8;
    B[0] = *(const short8*)(p);
    B[1] = *(const short8*)(p + 512);
    B[2] = *(const short8*)(p + 1024);
    B[3] = *(const short8*)(p + 1536);
  };
  auto process = [&](const short8* B, int id) {
    f32x4 c0 = {0.f,0.f,0.f,0.f}, c1 = {0.f,0.f,0.f,0.f};
    c0 = __builtin_amdgcn_mfma_f32_16x16x32_bf16(af[0][0], B[0], c0, 0,0,0);
    c1 = __builtin_amdgcn_mfma_f32_16x16x32_bf16(af[1][0], B[0], c1, 0,0,0);
    c0 = __builtin_amdgcn_mfma_f32_16x16x32_bf16(af[0][1], B[1], c0, 0,0,0);
    c1 = __builtin_amdgcn_mfma_f32_16x16x32_bf16(af[1][1], B[1], c1, 0,0,0);
    c0 = __builtin_amdgcn_mfma_f32_16x16x32_bf16(af[0][2], B[2], c0, 0,0,0);
    c1 = __builtin_amdgcn_mfma_f32_16x16x32_bf16(af[1][2], B[2], c1, 0,0,0);
    c0 = __builtin_amdgcn_mfma_f32_16x16x32_bf16(af[0][3], B[3], c0, 0,0,0);
    c1 = __builtin_amdgcn_mfma_f32_16x16x32_bf16(af[1][3], B[3], c1, 0,0,0);
    if (id < 64) {
      const f32x4 w0 = *(const f32x4*)&x0pt[id][eq];
      const f32x4 w1 = *(const f32x4*)&x0pt[id][16 + eq];
#pragma unroll
      for (int r = 0; r < 4; ++r) { p000[0][r] += w0[r]*c0[r]; p000[1][r] += w1[r]*c1[r]; }
    } else if (id < 96) {
      const int u = id - 64;
      const f32x4 w0 = *(const f32x4*)&z2wt[u][eq];
      const f32x4 w1 = *(const f32x4*)&z2wt[u][16 + eq];
#pragma unroll
      for (int r = 0; r < 4; ++r) { p0[0][r] += w0[r]*c0[r]; p0[1][r] += w1[r]*c1[r]; }
    } else if (id < 224) {
      const int u = (id - 96) >> 1;
      const f32x4 w0 = *(const f32x4*)&x0pt[u][eq];
      const f32x4 w1 = *(const f32x4*)&x0pt[u][16 + eq];
#pragma unroll
      for (int r = 0; r < 4; ++r) { p011[0][r] += w0[r]*c0[r]; p011[1][r] += w1[r]*c1[r]; }
    } else {
      const int u = (id - 224) >> 1;
#pragma unroll
      for (int r = 0; r < 4; ++r) {
        const float* xw0 = &x1wt[u][eq + r][0];
        const float* xw1 = &x1wt[u][16 + eq + r][0];
        p101[0][r][0] += xw0[0]*c0[r]; p101[0][r][1] += xw0[1]*c0[r]; p101[0][r][2] += xw0[2]*c0[r];
        p101[1][r][0] += xw1[0]*c1[r]; p101[1][r][1] += xw1[1]*c1[r]; p101[1][r][2] += xw1[2]*c1[r];
      }
    }
  };

  loadB(B0, wv); loadB(B1, wv + 4);
  int id = wv;
  for (int j = 0; j < 24; ++j) {
    loadB(B2, id + 8);  __builtin_amdgcn_sched_barrier(0); process(B0, id);
    loadB(B0, id + 12); __builtin_amdgcn_sched_barrier(0); process(B1, id + 4);
    loadB(B1, id + 16); __builtin_amdgcn_sched_barrier(0); process(B2, id + 8);
    id += 12;
  }

  // flush register partials -> msg_s (cross-wave accumulate)
  const int wcol = (wv & 1)*16 + nn;
#pragma unroll
  for (int t = 0; t < 2; ++t)
#pragma unroll
    for (int r = 0; r < 4; ++r) {
      const int e = t*16 + eq + r;
      atomicAdd(&msg_s[e][nn], a_s[e][0]*p000[t][r] + p0[t][r]);
      const float q = p011[t][r];
      atomicAdd(&msg_s[e][16 + wcol*3 + 0], a_s[e][1]*q + p101[t][r][0]);
      atomicAdd(&msg_s[e][16 + wcol*3 + 1], a_s[e][2]*q + p101[t][r][1]);
      atomicAdd(&msg_s[e][16 + wcol*3 + 2], a_s[e][3]*q + p101[t][r][2]);
    }
  __syncthreads();

  for (int i = tid; i < 32*112; i += 256) {
    int le = i / 112, slot = i - le*112;
    atomicAdd(&nm[dsts_s[le]*112 + slot], msg_s[le][slot]);
  }
}

// ---------------- K3: node gates via MFMA + fused pool (R8 version) --------
__global__ __launch_bounds__(256, 2) void k3_gate(const float* __restrict__ x,
                                                  const float* __restrict__ nm,
                                                  const short* __restrict__ bt,
                                                  const int* __restrict__ z,
                                                  const int* __restrict__ canonical,
                                                  float* __restrict__ xg,
                                                  float* __restrict__ sums,
                                                  float* __restrict__ cnt,
                                                  float cst_sig, float cst_tanh) {
  __shared__ short x0b[16][64];
  __shared__ short x1b[3][16][32];
  __shared__ short m0b[16][32];
  __shared__ float m0t[16][16];
  __shared__ float m1t[32][3][16];
  __shared__ float x1t[32][3][16];
  __shared__ float gs_s[16][20];
  __shared__ float gg_s[16][36];
  __shared__ float gv_s[16][100];
  const int tid = threadIdx.x;
  const int n0 = blockIdx.x * 16;

  for (int i = tid; i < 16*160; i += 256) {
    int n = i / 160, f = i - n*160;
    float v = x[(n0+n)*160 + f];
    if (f < 64) x0b[n][f] = f32_to_bf16_bits(v);
    else {
      int j = f - 64; int vv = j/3, m = j - vv*3;
      x1b[m][n][vv] = f32_to_bf16_bits(v);
      x1t[vv][m][n] = v;
    }
  }
  for (int i = tid; i < 16*112; i += 256) {
    int n = i / 112, f = i - n*112;
    float v = nm[(n0+n)*112 + f];
    if (f < 16) { m0b[n][f] = f32_to_bf16_bits(v); m0t[f][n] = v; }
    else { int j = f - 16; int u = j/3, m = j - u*3; m1t[u][m][n] = v; }
  }
  { int n = tid >> 4, k = tid & 15; m0b[n][16+k] = 0; }
  for (int i = tid; i < 320; i += 256) (&gs_s[0][0])[i] = 0.f;
  for (int i = tid; i < 576; i += 256) (&gg_s[0][0])[i] = 0.f;
  for (int i = tid; i < 1600; i += 256) (&gv_s[0][0])[i] = 0.f;
  __syncthreads();

  const int lane = tid & 63, wv = tid >> 6;
  const int quad = lane >> 4, nn = lane & 15;
  const int eq = quad * 4;
  const int wh = wv & 1, uw = wv >> 1;
  const int l8 = lane * 8;

  const short8 ax0a = *(const short8*)&x0b[nn][quad*8];
  const short8 ax0c = *(const short8*)&x0b[nn][32 + quad*8];
  short8 ax1[3];
#pragma unroll
  for (int m = 0; m < 3; ++m) ax1[m] = *(const short8*)&x1b[m][nn][quad*8];
  const short8 am0 = *(const short8*)&m0b[nn][quad*8];

  const short* b000 = bt;            // u*1024
  const short* b001 = bt + 16384;    // tau*1024
  const short* b110 = bt + 49152;    // u*512
  const short* b111 = bt + 65536;    // tau*512
  const short* b012 = bt + 98304;    // tau*512
  const short* b102 = bt + 131072;   // tau*1024

  float gs_p[4] = {}, gg_p[4] = {};
  float gv_p[3][4] = {};

  // T000: gs, u = wv + 4i (4 iters, K=64)
  {
    int u = wv;
    const short* p = b000 + u*1024 + l8;
    short8 ba = *(const short8*)p, bb = *(const short8*)(p + 512);
    for (int i = 0; i < 4; ++i) {
      const int un = (i < 3) ? u + 4 : u;
      const short* np = b000 + un*1024 + l8;
      short8 na = *(const short8*)np, nb = *(const short8*)(np + 512);
      __builtin_amdgcn_sched_barrier(0);
      f32x4 c = {0.f,0.f,0.f,0.f};
      c = __builtin_amdgcn_mfma_f32_16x16x32_bf16(ax0a, ba, c, 0,0,0);
      c = __builtin_amdgcn_mfma_f32_16x16x32_bf16(ax0c, bb, c, 0,0,0);
      const f32x4 t = *(const f32x4*)&m0t[u][eq];
#pragma unroll
      for (int r = 0; r < 4; ++r) gs_p[r] += t[r]*c[r];
      u = un; ba = na; bb = nb;
    }
  }
  // T110: gs, u = wv + 4i (8 iters, K=32), one B for 3 m-MFMAs
  {
    int u = wv;
    short8 s0 = *(const short8*)(b110 + u*512 + l8);
    for (int i = 0; i < 8; ++i) {
      const int un = (i < 7) ? u + 4 : u;
      short8 ns = *(const short8*)(b110 + un*512 + l8);
      __builtin_amdgcn_sched_barrier(0);
      f32x4 c0 = {0.f,0.f,0.f,0.f}, c1 = {0.f,0.f,0.f,0.f}, c2 = {0.f,0.f,0.f,0.f};
      c0 = __builtin_amdgcn_mfma_f32_16x16x32_bf16(ax1[0], s0, c0, 0,0,0);
      c1 = __builtin_amdgcn_mfma_f32_16x16x32_bf16(ax1[1], s0, c1, 0,0,0);
      c2 = __builtin_amdgcn_mfma_f32_16x16x32_bf16(ax1[2], s0, c2, 0,0,0);
      const f32x4 t0 = *(const f32x4*)&m1t[u][0][eq];
      const f32x4 t1 = *(const f32x4*)&m1t[u][1][eq];
      const f32x4 t2 = *(const f32x4*)&m1t[u][2][eq];
#pragma unroll
      for (int r = 0; r < 4; ++r) gs_p[r] += t0[r]*c0[r] + t1[r]*c1[r] + t2[r]*c2[r];
      u = un; s0 = ns;
    }
  }
  // T001: gg, u = uw + 2j, u < 16 (8 iters, K=64)
  {
    int u = uw;
    const short* p = b001 + (u*2 + wh)*1024 + l8;
    short8 ba = *(const short8*)p, bb = *(const short8*)(p + 512);
    for (int j = 0; j < 8; ++j) {
      const int un = (j < 7) ? u + 2 : u;
      const short* np = b001 + (un*2 + wh)*1024 + l8;
      short8 na = *(const short8*)np, nb = *(const short8*)(np + 512);
      __builtin_amdgcn_sched_barrier(0);
      f32x4 c = {0.f,0.f,0.f,0.f};
      c = __builtin_amdgcn_mfma_f32_16x16x32_bf16(ax0a, ba, c, 0,0,0);
      c = __builtin_amdgcn_mfma_f32_16x16x32_bf16(ax0c, bb, c, 0,0,0);
      const f32x4 t = *(const f32x4*)&m0t[u][eq];
#pragma unroll
      for (int r = 0; r < 4; ++r) gg_p[r] += t[r]*c[r];
      u = un; ba = na; bb = nb;
    }
  }
  // T111: gg, u = uw + 2j, u < 32 (16 iters, K=32), one B for 3 m-MFMAs
  {
    int u = uw;
    short8 s0 = *(const short8*)(b111 + (u*2 + wh)*512 + l8);
    for (int j = 0; j < 16; ++j) {
      const int un = (j < 15) ? u + 2 : u;
      short8 ns = *(const short8*)(b111 + (un*2 + wh)*512 + l8);
      __builtin_amdgcn_sched_barrier(0);
      f32x4 c0 = {0.f,0.f,0.f,0.f}, c1 = {0.f,0.f,0.f,0.f}, c2 = {0.f,0.f,0.f,0.f};
      c0 = __builtin_amdgcn_mfma_f32_16x16x32_bf16(ax1[0], s0, c0, 0,0,0);
      c1 = __builtin_amdgcn_mfma_f32_16x16x32_bf16(ax1[1], s0, c1, 0,0,0);
      c2 = __builtin_amdgcn_mfma_f32_16x16x32_bf16(ax1[2], s0, c2, 0,0,0);
      const f32x4 t0 = *(const f32x4*)&m1t[u][0][eq];
      const f32x4 t1 = *(const f32x4*)&m1t[u][1][eq];
      const f32x4 t2 = *(const f32x4*)&m1t[u][2][eq];
#pragma unroll
      for (int r = 0; r < 4; ++r) gg_p[r] += t0[r]*c0[r] + t1[r]*c1[r] + t2[r]*c2[r];
      u = un; s0 = ns;
    }
  }
  // T012: gv, v = uw + 2j, v < 32 (16 iters, K=32), A = m0
  {
    int v = uw;
    short8 s0 = *(const short8*)(b012 + (v*2 + wh)*512 + l8);
    for (int j = 0; j < 16; ++j) {
      const int vn = (j < 15) ? v + 2 : v;
      short8 ns = *(const short8*)(b012 + (vn*2 + wh)*512 + l8);
      __builtin_amdgcn_sched_barrier(0);
      f32x4 c = {0.f,0.f,0.f,0.f};
      c = __builtin_amdgcn_mfma_f32_16x16x32_bf16(am0, s0, c, 0,0,0);
#pragma unroll
      for (int m = 0; m < 3; ++m) {
        const f32x4 t = *(const f32x4*)&x1t[v][m][eq];
#pragma unroll
        for (int r = 0; r < 4; ++r) gv_p[m][r] += t[r]*c[r];
      }
      v = vn; s0 = ns;
    }
  }
  // T102: gv, u = uw + 2j, u < 32 (16 iters, K=64)
  {
    int u = uw;
    const short* p = b102 + (u*2 + wh)*1024 + l8;
    short8 ba = *(const short8*)p, bb = *(const short8*)(p + 512);
    for (int j = 0; j < 16; ++j) {
      const int un = (j < 15) ? u + 2 : u;
      const short* np = b102 + (un*2 + wh)*1024 + l8;
      short8 na = *(const short8*)np, nb = *(const short8*)(np + 512);
      __builtin_amdgcn_sched_barrier(0);
      f32x4 c = {0.f,0.f,0.f,0.f};
      c = __builtin_amdgcn_mfma_f32_16x16x32_bf16(ax0a, ba, c, 0,0,0);
      c = __builtin_amdgcn_mfma_f32_16x16x32_bf16(ax0c, bb, c, 0,0,0);
#pragma unroll
      for (int m = 0; m < 3; ++m) {
        const f32x4 t = *(const f32x4*)&m1t[u][m][eq];
#pragma unroll
        for (int r = 0; r < 4; ++r) gv_p[m][r] += t[r]*c[r];
      }
      u = un; ba = na; bb = nb;
    }
  }

#pragma unroll
  for (int r = 0; r < 4; ++r) {
    atomicAdd(&gs_s[eq + r][nn], gs_p[r]);
    atomicAdd(&gg_s[eq + r][wh*16 + nn], gg_p[r]);
#pragma unroll
    for (int m = 0; m < 3; ++m)
      atomicAdd(&gv_s[eq + r][(wh*16 + nn)*3 + m], gv_p[m][r]);
  }
  __syncthreads();

  // epilogue + fused masked canonical pooling
  for (int i = tid; i < 16*112; i += 256) {
    int n = i / 112, f = i - n*112;
    float o;
    if (f < 16) {
      o = cst_sig / (1.f + expf(-PW_G01f * gs_s[n][f]));
    } else {
      int j = f - 16; int w = j/3;
      float gate = cst_tanh * tanhf(PW_G01f * gg_s[n][w]);
      o = gate * (PW_G2f * INV_SQRT3f) * gv_s[n][j];
    }
    const int gn = n0 + n;
    xg[gn*112 + f] = o;
    if (z[gn] > 1) {
      const int c = canonical[gn];
      atomicAdd(&sums[c*112 + f], o);
      if (f == 0) atomicAdd(&cnt[c], 1.f);
    }
  }
}

// ---------------- K5: quadratic head -> th (R8 version) --------------------
__global__ __launch_bounds__(256) void k5_thead(const float* __restrict__ sums,
                                                const float* __restrict__ cnt,
                                                const float* __restrict__ Wa,
                                                const float* __restrict__ Wb,
                                                const float* __restrict__ Wc,
                                                const float* __restrict__ wdt,
                                                float* __restrict__ th) {
  __shared__ float xh_s[8][112];
  __shared__ float cm_s[8][1024];
  __shared__ float red[256];
  const int tid = threadIdx.x;
  const int n0 = blockIdx.x * 8;
  for (int i = tid; i < 8*112; i += 256) {
    int n = i / 112, j = i - n*112;
    float cv = fmaxf(cnt[n0+n], 1.f);
    xh_s[n][j] = sums[(n0+n)*112 + j] / cv;
  }
  __syncthreads();
  for (int i = tid; i < 8192; i += 256) {
    int n = i >> 10, uv = i & 1023, u = uv >> 5, v = uv & 31;
    const float* hh = xh_s[n] + 16;
    cm_s[n][uv] = hh[u*3]*hh[v*3] + hh[u*3+1]*hh[v*3+1] + hh[u*3+2]*hh[v*3+2];
  }
  __syncthreads();
  {                                     // Wd dot split across 2 threads
    const int hs = tid >> 7, p = tid & 127;
    const int n = p >> 4, k = p & 15;
    float wd = 0.f;
    const float* cp = cm_s[n] + hs*512;
    const float* wp = wdt + k*1024 + hs*512;
#pragma unroll 4
    for (int uv = 0; uv < 512; uv += 4) {
      const f32x4 a = *(const f32x4*)&cp[uv];
      const f32x4 bq = *(const f32x4*)&wp[uv];
      wd += a[0]*bq[0] + a[1]*bq[1] + a[2]*bq[2] + a[3]*bq[3];
    }
    red[tid] = wd;
  }
  __syncthreads();
  if (tid < 128) {
    int n = tid >> 4, k = tid & 15;
    float sA = 0.f;
    for (int v = 0; v < 16; ++v) sA += Wa[k*16+v]*xh_s[n][v];
    float wd = red[tid] + red[tid + 128];
    th[(n0+n)*112 + k] = PW_H0f*(xh_s[n][k]*sA + INV_SQRT3f*wd);
  }
  {
    int n = tid >> 5, j = tid & 31;
    float wb = 0.f, wc = 0.f;
    for (int u = 0; u < 16; ++u) wb += Wb[u*32+j]*xh_s[n][u];
    for (int v = 0; v < 16; ++v) wc += Wc[j*16+v]*xh_s[n][v];
    float cb = PW_H1f * INV_SQRT3f * (wb + wc);
    const float* hh = xh_s[n] + 16;
    float* o = th + (n0+n)*112 + 16 + j*3;
    o[0] = cb*hh[j*3]; o[1] = cb*hh[j*3+1]; o[2] = cb*hh[j*3+2];
  }
}

// ---------------- K6: select + output linear (transposed W reads) ----------
__global__ __launch_bounds__(256) void k6_out(const float* __restrict__ xg,
                                              const float* __restrict__ th,
                                              const int* __restrict__ z,
                                              const int* __restrict__ canonical,
                                              const float* __restrict__ wl0t,
                                              const float* __restrict__ wl1t,
                                              float* __restrict__ out) {
  int idx = blockIdx.x * 256 + threadIdx.x;
  int n = idx / 112, j = idx - n*112;
  const float* yr = (z[n] > 1) ? (th + canonical[n]*112) : (xg + n*112);
  float o = 0.f;
  if (j < 16) {
    const float* wp = wl0t + j*16;
#pragma unroll 4
    for (int v = 0; v < 16; ++v) o += yr[v]*wp[v];
    o *= 0.25f;
  } else {
    int jj = j - 16, w = jj / 3, m = jj - w*3;
    const float* wp = wl1t + w*32;
#pragma unroll 4
    for (int u = 0; u < 32; ++u) o += yr[16 + u*3 + m]*wp[u];
    o *= RSQRT32f;
  }
  out[idx] = o;
}

// ---------------- host: replicate numpy's trapz normalization constants ----
namespace {
struct Csts {
  float silu, sig, tanh_;
  Csts() {
    const int NPT = 200001;
    const double a = -12.0, b = 12.0;
    const double dx = (b - a) / (NPT - 1);
    double s1 = 0.0, s2 = 0.0, s3 = 0.0;
    for (int i = 0; i < NPT; ++i) {
      double xv = a + dx*i;
      double pdf = std::exp(-0.5*xv*xv) / std::sqrt(2.0*M_PI);
      double sg = 1.0 / (1.0 + std::exp(-xv));
      double f1 = xv*sg, f2 = sg, f3 = std::tanh(xv);
      double wg = (i == 0 || i == NPT-1) ? 0.5 : 1.0;
      s1 += wg*f1*f1*pdf; s2 += wg*f2*f2*pdf; s3 += wg*f3*f3*pdf;
    }
    silu  = (float)(1.0/std::sqrt(s1*dx));
    sig   = (float)(1.0/std::sqrt(s2*dx));
    tanh_ = (float)(1.0/std::sqrt(s3*dx));
  }
};
}  // namespace

extern "C" void kernel_launch(void* const* d_in, const int* in_sizes, int n_in,
                              void* d_out, int out_size, void* d_ws, size_t ws_size,
                              hipStream_t stream) {
  const float* x     = (const float*)d_in[0];
  const float* ea    = (const float*)d_in[1];
  const float* W1    = (const float*)d_in[2];
  const float* W2    = (const float*)d_in[3];
  const float* Wg000 = (const float*)d_in[4];
  const float* Wg110 = (const float*)d_in[5];
  const float* Wg001 = (const float*)d_in[6];
  const float* Wg111 = (const float*)d_in[7];
  const float* Wg012 = (const float*)d_in[8];
  const float* Wg102 = (const float*)d_in[9];
  const float* Wa    = (const float*)d_in[10];
  const float* Wb    = (const float*)d_in[11];
  const float* Wc    = (const float*)d_in[12];
  const float* Wd    = (const float*)d_in[13];
  const float* WL0   = (const float*)d_in[14];
  const float* WL1   = (const float*)d_in[15];
  const int* ei      = (const int*)d_in[16];
  const int* z       = (const int*)d_in[17];
  const int* canonical = (const int*)d_in[18];
  float* out = (float*)d_out;

  // workspace layout (floats); no trailing backslashes in comments (R9 bug)
  float* ws   = (float*)d_ws;
  short* hbf  = (short*)ws;            // 3,072,000 bf16
  short* w2s  = (short*)(ws + 1536000);//   589,824 bf16 (swizzled fragments)
  short* bt   = (short*)(ws + 1831000);//   196,608 bf16 gate tables (swizzled)
  float* nm   = ws + 1930000;          //   896,000 (zeroed, contiguous block)
  float* sums = ws + 2826000;          //   896,000 (zeroed)
  float* cnt  = ws + 3722000;          //     8,000 (zeroed)
  float* xg   = ws + 3730000;          //   896,000
  float* th   = ws + 4626000;          //   896,000
  float* wdt  = ws + 5522000;          //    16,384
  float* wl0t = ws + 5538384;          //       256
  float* wl1t = ws + 5538640;          //     1,024  -> total 5,539,664 floats

  static const Csts C;                 // host-only; safe under graph capture

  k_prep<<<6171, 256, 0, stream>>>(W2, Wg000, Wg110, Wg001, Wg111, Wg012,
                                   Wg102, Wd, WL0, WL1, ea, W1,
                                   w2s, bt, wdt, wl0t, wl1t, hbf, nm, C.silu);
  k2_edge_msg<<<750, 256, 0, stream>>>(x, ea, w2s, hbf, ei, nm);
  k3_gate<<<500, 256, 0, stream>>>(x, nm, bt, z, canonical, xg, sums, cnt,
                                   C.sig, C.tanh_);
  k5_thead<<<1000, 256, 0, stream>>>(sums, cnt, Wa, Wb, Wc, wdt, th);
  k6_out<<<3500, 256, 0, stream>>>(xg, th, z, canonical, wl0t, wl1t, out);
}

// Round 13
// 283.456 us; speedup vs baseline: 1.1992x; 1.1992x over previous
//
#include <hip/hip_runtime.h>
#include <hip/hip_bf16.h>
#include <cmath>

// ---------------------------------------------------------------------------
// HeavyEncoderLayer, MI355X. R13 = union of proven-best pieces:
//  - k2: R8/R11-proven launch_bounds(256,2) (R12's (256,4) forced VGPR 64 +
//    scratch spills, WRITE 10.5->109MB, 80->137us. Reverted.)
//  - k3/k5: R8-proven versions.
//  - k_prep: merged W2-swizzle + gate tables + transposes + k1 + zero-fill
//    (R12's dispatch-count reduction, kept).
// ---------------------------------------------------------------------------

#define N_NODES 8000
#define N_EDGES 24000

#define INV_SQRT3f 0.57735026918962576f
#define PW_MSG0f 0.10206207261596575f   /* sqrt(1/96) */
#define PW1f     0.10206207261596575f   /* PW_MSG1*INV_SQRT3 == sqrt(1/96) */
#define PW_G01f  0.022097086912079608f  /* sqrt(1/2048) */
#define PW_G2f   0.034232659844072866f  /* sqrt(3/2560) */
#define PW_H0f   0.031008683647302115f  /* sqrt(1/1040) */
#define PW_H1f   0.30618621784789724f   /* sqrt(3/32) */
#define RSQRT128f 0.08838834764831845f
#define RSQRT32f  0.17677669529663687f

typedef short short8 __attribute__((ext_vector_type(8)));
typedef short short4v __attribute__((ext_vector_type(4)));
typedef float f32x4 __attribute__((ext_vector_type(4)));

__device__ inline short f32_to_bf16_bits(float v) {
  unsigned int b = __builtin_bit_cast(unsigned int, v);
  b += 0x7fffu + ((b >> 16) & 1u);        // RNE (no NaN inputs here)
  return (short)(b >> 16);
}

// ---------------- unified prep: W2 swizzle, Wg tables, k1, zero-fill -------
// b <  576 : W2 -> w2s swizzled fragments
// b < 1344 : gate tables, fragment order
// b < 1413 : Wd / WL0 / WL1 transposes
// b < 4413 : k1 edge MLP -> bf16
// b < 6171 : zero nm/sums/cnt
__global__ __launch_bounds__(256) void k_prep(const float* __restrict__ W2,
                                              const float* __restrict__ Wg000,
                                              const float* __restrict__ Wg110,
                                              const float* __restrict__ Wg001,
                                              const float* __restrict__ Wg111,
                                              const float* __restrict__ Wg012,
                                              const float* __restrict__ Wg102,
                                              const float* __restrict__ Wd,
                                              const float* __restrict__ WL0,
                                              const float* __restrict__ WL1,
                                              const float* __restrict__ ea,
                                              const float* __restrict__ W1,
                                              short* __restrict__ w2s,
                                              short* __restrict__ bt,
                                              float* __restrict__ wdt,
                                              float* __restrict__ wl0t,
                                              float* __restrict__ wl1t,
                                              short* __restrict__ hbf,
                                              float* __restrict__ zero_base,
                                              float cst_silu) {
  const int b = blockIdx.x, tid = threadIdx.x;
  if (b < 576) {                         // W2 -> w2s (swizzled)
    __shared__ float tile[32][33];
    const int kt = b & 3, ct = b >> 2;
    const int k0 = kt*32, c0 = ct*32;
    const int tx = tid & 31, ty = tid >> 5;   // 32 x 8
#pragma unroll
    for (int i = 0; i < 4; ++i) {
      int r = ty + i*8;
      tile[r][tx] = W2[(k0+r)*4608 + c0 + tx];
    }
    __syncthreads();
#pragma unroll
    for (int i = 0; i < 4; ++i) {
      int r = ty + i*8;
      const int c = c0 + r, k = k0 + tx;
      const int id = (c < 1024) ? (c >> 4)
                   : (c < 4096) ? ((c + 512) >> 4) : ((c - 3072) >> 4);
      const int nn = c & 15, ks = k >> 5, quad = (k >> 3) & 3, jj = k & 7;
      w2s[id*2048 + ks*512 + (quad*16 + nn)*8 + jj] = f32_to_bf16_bits(tile[tx][r]);
    }
  } else if (b < 1344) {                 // gate tables, fragment order
    int i = (b - 576) * 256 + tid;       // < 196608 exact
    float v;
    if (i < 16384) {                     // b000s
      int u = i >> 10, r = i & 1023;
      int ks = r >> 9, lane = (r >> 3) & 63, j = r & 7;
      int k = ks*32 + (lane >> 4)*8 + j, nn = lane & 15;
      v = Wg000[u*1024 + k*16 + nn];
    } else if (i < 49152) {              // b001s
      int o = i - 16384;
      int tau = o >> 10, r = o & 1023;
      int u = tau >> 1, wh = tau & 1;
      int ks = r >> 9, lane = (r >> 3) & 63, j = r & 7;
      int k = ks*32 + (lane >> 4)*8 + j, nn = lane & 15;
      v = Wg001[u*2048 + k*32 + wh*16 + nn];
    } else if (i < 65536) {              // b110s
      int o = i - 49152;
      int u = o >> 9, r = o & 511;
      int lane = r >> 3, j = r & 7;
      int k = (lane >> 4)*8 + j, nn = lane & 15;
      v = INV_SQRT3f * Wg110[u*512 + k*16 + nn];
    } else if (i < 98304) {              // b111s
      int o = i - 65536;
      int tau = o >> 9, r = o & 511;
      int u = tau >> 1, wh = tau & 1;
      int lane = r >> 3, j = r & 7;
      int k = (lane >> 4)*8 + j, nn = lane & 15;
      v = INV_SQRT3f * Wg111[u*1024 + k*32 + wh*16 + nn];
    } else if (i < 131072) {             // b012s (k=u, padded)
      int o = i - 98304;
      int tau = o >> 9, r = o & 511;
      int vv = tau >> 1, wh = tau & 1;
      int lane = r >> 3, j = r & 7;
      int k = (lane >> 4)*8 + j, nn = lane & 15;
      v = (k < 16) ? Wg012[k*1024 + vv*32 + wh*16 + nn] : 0.f;
    } else {                             // b102s
      int o = i - 131072;
      int tau = o >> 10, r = o & 1023;
      int u = tau >> 1, wh = tau & 1;
      int ks = r >> 9, lane = (r >> 3) & 63, j = r & 7;
      int k = ks*32 + (lane >> 4)*8 + j, nn = lane & 15;
      v = Wg102[u*2048 + k*32 + wh*16 + nn];
    }
    bt[i] = f32_to_bf16_bits(v);
  } else if (b < 1413) {                 // small f32 transposes
    int i = (b - 1344) * 256 + tid;      // < 17664 exact
    if (i < 16384) {                     // Wdt[k][uv] = Wd[uv*16+k]
      int k = i >> 10, uv = i & 1023;
      wdt[i] = Wd[uv*16 + k];
    } else if (i < 16640) {              // WL0t[j][v]
      int j = i - 16384; int jj = j >> 4, v = j & 15;
      wl0t[j] = WL0[v*16 + jj];
    } else if (i < 17664) {              // WL1t[w][u]
      int j = i - 16640; int w = j >> 5, u = j & 31;
      wl1t[j] = WL1[u*32 + w];
    }
  } else if (b < 4413) {                 // k1: edge MLP -> bf16 (x4 vec)
    int idx = (b - 1413) * 256 + tid;    // e*32 + q, 768000 exact
    int e = idx >> 5, q = idx & 31;
    const float a0 = ea[e*4+0], a1 = ea[e*4+1], a2 = ea[e*4+2], a3 = ea[e*4+3];
    const float4 w0 = *(const float4*)&W1[q*4];
    const float4 w1 = *(const float4*)&W1[128 + q*4];
    const float4 w2 = *(const float4*)&W1[256 + q*4];
    const float4 w3 = *(const float4*)&W1[384 + q*4];
    float s[4] = {0.5f*(a0*w0.x + a1*w1.x + a2*w2.x + a3*w3.x),
                  0.5f*(a0*w0.y + a1*w1.y + a2*w2.y + a3*w3.y),
                  0.5f*(a0*w0.z + a1*w1.z + a2*w2.z + a3*w3.z),
                  0.5f*(a0*w0.w + a1*w1.w + a2*w2.w + a3*w3.w)};
    short4v o;
#pragma unroll
    for (int i = 0; i < 4; ++i) {
      float sg = 1.f / (1.f + expf(-s[i]));
      o[i] = f32_to_bf16_bits(cst_silu * s[i] * sg * RSQRT128f);
    }
    *(short4v*)&hbf[idx*4] = o;
  } else {                               // zero nm/sums/cnt (1,800,000 floats)
    int i = (b - 4413) * 256 + tid;      // float4 index
    if (i < 450000) {
      f32x4 zz = {0.f,0.f,0.f,0.f};
      *(f32x4*)&zero_base[i*4] = zz;
    }
  }
}

// ---------------- K2: MFMA edge GEMM (R8-proven: (256,2), no spills) -------
__global__ __launch_bounds__(256, 2) void k2_edge_msg(
    const float* __restrict__ x, const float* __restrict__ ea,
    const short* __restrict__ w2s, const short* __restrict__ hbf,
    const int* __restrict__ ei, float* __restrict__ nm) {
  __shared__ float msg_s[32][116];     // pad 116: flush conflicts 4->2-way
  __shared__ float x0pt[64][32];       // [u][e] PW1*xs0
  __shared__ float z2wt[32][32];       // [u][e] PW0*inv3*(xs1[u].a1)
  __shared__ float x1wt[32][32][3];    // [u][e][m] PW1*a0*xs1[u][m]
  __shared__ float a_s[32][4];
  __shared__ int srcs_s[32], dsts_s[32];

  const int tid = threadIdx.x;
  const int e0 = blockIdx.x * 32;

  if (tid < 32) { srcs_s[tid] = ei[e0+tid]; dsts_s[tid] = ei[N_EDGES + e0 + tid]; }
  if (tid < 128) a_s[tid>>2][tid&3] = ea[e0*4 + tid];
  for (int i = tid; i < 32*116; i += 256) (&msg_s[0][0])[i] = 0.f;
  __syncthreads();

  for (int i = tid; i < 2048; i += 256) {      // coalesced x0 gather
    int e = i >> 6, u = i & 63;
    x0pt[u][e] = PW1f * x[srcs_s[e]*160 + u];
  }
  for (int i = tid; i < 1024; i += 256) {
    int e = i >> 5, u = i & 31;
    const float* xp = &x[srcs_s[e]*160 + 64 + u*3];
    float m0v = xp[0], m1v = xp[1], m2v = xp[2];
    float a0 = a_s[e][0];
    z2wt[u][e] = PW_MSG0f * INV_SQRT3f *
                 (m0v*a_s[e][1] + m1v*a_s[e][2] + m2v*a_s[e][3]);
    x1wt[u][e][0] = PW1f * a0 * m0v;
    x1wt[u][e][1] = PW1f * a0 * m1v;
    x1wt[u][e][2] = PW1f * a0 * m2v;
  }
  __syncthreads();

  const int lane = tid & 63, wv = tid >> 6;
  const int quad = lane >> 4, nn = lane & 15;
  const int eq = quad * 4;

  short8 af[2][4];
#pragma unroll
  for (int t = 0; t < 2; ++t)
#pragma unroll
    for (int ks = 0; ks < 4; ++ks)
      af[t][ks] = *(const short8*)&hbf[(e0 + t*16 + nn)*128 + ks*32 + quad*8];

  float p000[2][4] = {};      // s000: x0pt fold (x a0 at flush)
  float p0[2][4] = {};        // s110: z2wt fold
  float p011[2][4] = {};      // s011: x0pt fold (x a1[m] at flush)
  float p101[2][4][3] = {};   // s101: x1wt fold

  short8 B0[4], B1[4], B2[4];
  auto loadB = [&](short8* B, int id) {
    const int idc = (id < 287) ? id : 287;     // clamp tail prefetch
    const short* p = w2s + idc*2048 + lane*8;
    B[0] = *(const short8*)(p);
    B[1] = *(const short8*)(p + 512);
    B[2] = *(const short8*)(p + 1024);
    B[3] = *(const short8*)(p + 1536);
  };
  auto process = [&](const short8* B, int id) {
    f32x4 c0 = {0.f,0.f,0.f,0.f}, c1 = {0.f,0.f,0.f,0.f};
    c0 = __builtin_amdgcn_mfma_f32_16x16x32_bf16(af[0][0], B[0], c0, 0,0,0);
    c1 = __builtin_amdgcn_mfma_f32_16x16x32_bf16(af[1][0], B[0], c1, 0,0,0);
    c0 = __builtin_amdgcn_mfma_f32_16x16x32_bf16(af[0][1], B[1], c0, 0,0,0);
    c1 = __builtin_amdgcn_mfma_f32_16x16x32_bf16(af[1][1], B[1], c1, 0,0,0);
    c0 = __builtin_amdgcn_mfma_f32_16x16x32_bf16(af[0][2], B[2], c0, 0,0,0);
    c1 = __builtin_amdgcn_mfma_f32_16x16x32_bf16(af[1][2], B[2], c1, 0,0,0);
    c0 = __builtin_amdgcn_mfma_f32_16x16x32_bf16(af[0][3], B[3], c0, 0,0,0);
    c1 = __builtin_amdgcn_mfma_f32_16x16x32_bf16(af[1][3], B[3], c1, 0,0,0);
    if (id < 64) {
      const f32x4 w0 = *(const f32x4*)&x0pt[id][eq];
      const f32x4 w1 = *(const f32x4*)&x0pt[id][16 + eq];
#pragma unroll
      for (int r = 0; r < 4; ++r) { p000[0][r] += w0[r]*c0[r]; p000[1][r] += w1[r]*c1[r]; }
    } else if (id < 96) {
      const int u = id - 64;
      const f32x4 w0 = *(const f32x4*)&z2wt[u][eq];
      const f32x4 w1 = *(const f32x4*)&z2wt[u][16 + eq];
#pragma unroll
      for (int r = 0; r < 4; ++r) { p0[0][r] += w0[r]*c0[r]; p0[1][r] += w1[r]*c1[r]; }
    } else if (id < 224) {
      const int u = (id - 96) >> 1;
      const f32x4 w0 = *(const f32x4*)&x0pt[u][eq];
      const f32x4 w1 = *(const f32x4*)&x0pt[u][16 + eq];
#pragma unroll
      for (int r = 0; r < 4; ++r) { p011[0][r] += w0[r]*c0[r]; p011[1][r] += w1[r]*c1[r]; }
    } else {
      const int u = (id - 224) >> 1;
#pragma unroll
      for (int r = 0; r < 4; ++r) {
        const float* xw0 = &x1wt[u][eq + r][0];
        const float* xw1 = &x1wt[u][16 + eq + r][0];
        p101[0][r][0] += xw0[0]*c0[r]; p101[0][r][1] += xw0[1]*c0[r]; p101[0][r][2] += xw0[2]*c0[r];
        p101[1][r][0] += xw1[0]*c1[r]; p101[1][r][1] += xw1[1]*c1[r]; p101[1][r][2] += xw1[2]*c1[r];
      }
    }
  };

  loadB(B0, wv); loadB(B1, wv + 4);
  int id = wv;
  for (int j = 0; j < 24; ++j) {
    loadB(B2, id + 8);  __builtin_amdgcn_sched_barrier(0); process(B0, id);
    loadB(B0, id + 12); __builtin_amdgcn_sched_barrier(0); process(B1, id + 4);
    loadB(B1, id + 16); __builtin_amdgcn_sched_barrier(0); process(B2, id + 8);
    id += 12;
  }

  // flush register partials -> msg_s (cross-wave accumulate)
  const int wcol = (wv & 1)*16 + nn;
#pragma unroll
  for (int t = 0; t < 2; ++t)
#pragma unroll
    for (int r = 0; r < 4; ++r) {
      const int e = t*16 + eq + r;
      atomicAdd(&msg_s[e][nn], a_s[e][0]*p000[t][r] + p0[t][r]);
      const float q = p011[t][r];
      atomicAdd(&msg_s[e][16 + wcol*3 + 0], a_s[e][1]*q + p101[t][r][0]);
      atomicAdd(&msg_s[e][16 + wcol*3 + 1], a_s[e][2]*q + p101[t][r][1]);
      atomicAdd(&msg_s[e][16 + wcol*3 + 2], a_s[e][3]*q + p101[t][r][2]);
    }
  __syncthreads();

  for (int i = tid; i < 32*112; i += 256) {
    int le = i / 112, slot = i - le*112;
    atomicAdd(&nm[dsts_s[le]*112 + slot], msg_s[le][slot]);
  }
}

// ---------------- K3: node gates via MFMA + fused pool (R8 version) --------
__global__ __launch_bounds__(256, 2) void k3_gate(const float* __restrict__ x,
                                                  const float* __restrict__ nm,
                                                  const short* __restrict__ bt,
                                                  const int* __restrict__ z,
                                                  const int* __restrict__ canonical,
                                                  float* __restrict__ xg,
                                                  float* __restrict__ sums,
                                                  float* __restrict__ cnt,
                                                  float cst_sig, float cst_tanh) {
  __shared__ short x0b[16][64];
  __shared__ short x1b[3][16][32];
  __shared__ short m0b[16][32];
  __shared__ float m0t[16][16];
  __shared__ float m1t[32][3][16];
  __shared__ float x1t[32][3][16];
  __shared__ float gs_s[16][20];
  __shared__ float gg_s[16][36];
  __shared__ float gv_s[16][100];
  const int tid = threadIdx.x;
  const int n0 = blockIdx.x * 16;

  for (int i = tid; i < 16*160; i += 256) {
    int n = i / 160, f = i - n*160;
    float v = x[(n0+n)*160 + f];
    if (f < 64) x0b[n][f] = f32_to_bf16_bits(v);
    else {
      int j = f - 64; int vv = j/3, m = j - vv*3;
      x1b[m][n][vv] = f32_to_bf16_bits(v);
      x1t[vv][m][n] = v;
    }
  }
  for (int i = tid; i < 16*112; i += 256) {
    int n = i / 112, f = i - n*112;
    float v = nm[(n0+n)*112 + f];
    if (f < 16) { m0b[n][f] = f32_to_bf16_bits(v); m0t[f][n] = v; }
    else { int j = f - 16; int u = j/3, m = j - u*3; m1t[u][m][n] = v; }
  }
  { int n = tid >> 4, k = tid & 15; m0b[n][16+k] = 0; }
  for (int i = tid; i < 320; i += 256) (&gs_s[0][0])[i] = 0.f;
  for (int i = tid; i < 576; i += 256) (&gg_s[0][0])[i] = 0.f;
  for (int i = tid; i < 1600; i += 256) (&gv_s[0][0])[i] = 0.f;
  __syncthreads();

  const int lane = tid & 63, wv = tid >> 6;
  const int quad = lane >> 4, nn = lane & 15;
  const int eq = quad * 4;
  const int wh = wv & 1, uw = wv >> 1;
  const int l8 = lane * 8;

  const short8 ax0a = *(const short8*)&x0b[nn][quad*8];
  const short8 ax0c = *(const short8*)&x0b[nn][32 + quad*8];
  short8 ax1[3];
#pragma unroll
  for (int m = 0; m < 3; ++m) ax1[m] = *(const short8*)&x1b[m][nn][quad*8];
  const short8 am0 = *(const short8*)&m0b[nn][quad*8];

  const short* b000 = bt;            // u*1024
  const short* b001 = bt + 16384;    // tau*1024
  const short* b110 = bt + 49152;    // u*512
  const short* b111 = bt + 65536;    // tau*512
  const short* b012 = bt + 98304;    // tau*512
  const short* b102 = bt + 131072;   // tau*1024

  float gs_p[4] = {}, gg_p[4] = {};
  float gv_p[3][4] = {};

  // T000: gs, u = wv + 4i (4 iters, K=64)
  {
    int u = wv;
    const short* p = b000 + u*1024 + l8;
    short8 ba = *(const short8*)p, bb = *(const short8*)(p + 512);
    for (int i = 0; i < 4; ++i) {
      const int un = (i < 3) ? u + 4 : u;
      const short* np = b000 + un*1024 + l8;
      short8 na = *(const short8*)np, nb = *(const short8*)(np + 512);
      __builtin_amdgcn_sched_barrier(0);
      f32x4 c = {0.f,0.f,0.f,0.f};
      c = __builtin_amdgcn_mfma_f32_16x16x32_bf16(ax0a, ba, c, 0,0,0);
      c = __builtin_amdgcn_mfma_f32_16x16x32_bf16(ax0c, bb, c, 0,0,0);
      const f32x4 t = *(const f32x4*)&m0t[u][eq];
#pragma unroll
      for (int r = 0; r < 4; ++r) gs_p[r] += t[r]*c[r];
      u = un; ba = na; bb = nb;
    }
  }
  // T110: gs, u = wv + 4i (8 iters, K=32), one B for 3 m-MFMAs
  {
    int u = wv;
    short8 s0 = *(const short8*)(b110 + u*512 + l8);
    for (int i = 0; i < 8; ++i) {
      const int un = (i < 7) ? u + 4 : u;
      short8 ns = *(const short8*)(b110 + un*512 + l8);
      __builtin_amdgcn_sched_barrier(0);
      f32x4 c0 = {0.f,0.f,0.f,0.f}, c1 = {0.f,0.f,0.f,0.f}, c2 = {0.f,0.f,0.f,0.f};
      c0 = __builtin_amdgcn_mfma_f32_16x16x32_bf16(ax1[0], s0, c0, 0,0,0);
      c1 = __builtin_amdgcn_mfma_f32_16x16x32_bf16(ax1[1], s0, c1, 0,0,0);
      c2 = __builtin_amdgcn_mfma_f32_16x16x32_bf16(ax1[2], s0, c2, 0,0,0);
      const f32x4 t0 = *(const f32x4*)&m1t[u][0][eq];
      const f32x4 t1 = *(const f32x4*)&m1t[u][1][eq];
      const f32x4 t2 = *(const f32x4*)&m1t[u][2][eq];
#pragma unroll
      for (int r = 0; r < 4; ++r) gs_p[r] += t0[r]*c0[r] + t1[r]*c1[r] + t2[r]*c2[r];
      u = un; s0 = ns;
    }
  }
  // T001: gg, u = uw + 2j, u < 16 (8 iters, K=64)
  {
    int u = uw;
    const short* p = b001 + (u*2 + wh)*1024 + l8;
    short8 ba = *(const short8*)p, bb = *(const short8*)(p + 512);
    for (int j = 0; j < 8; ++j) {
      const int un = (j < 7) ? u + 2 : u;
      const short* np = b001 + (un*2 + wh)*1024 + l8;
      short8 na = *(const short8*)np, nb = *(const short8*)(np + 512);
      __builtin_amdgcn_sched_barrier(0);
      f32x4 c = {0.f,0.f,0.f,0.f};
      c = __builtin_amdgcn_mfma_f32_16x16x32_bf16(ax0a, ba, c, 0,0,0);
      c = __builtin_amdgcn_mfma_f32_16x16x32_bf16(ax0c, bb, c, 0,0,0);
      const f32x4 t = *(const f32x4*)&m0t[u][eq];
#pragma unroll
      for (int r = 0; r < 4; ++r) gg_p[r] += t[r]*c[r];
      u = un; ba = na; bb = nb;
    }
  }
  // T111: gg, u = uw + 2j, u < 32 (16 iters, K=32), one B for 3 m-MFMAs
  {
    int u = uw;
    short8 s0 = *(const short8*)(b111 + (u*2 + wh)*512 + l8);
    for (int j = 0; j < 16; ++j) {
      const int un = (j < 15) ? u + 2 : u;
      short8 ns = *(const short8*)(b111 + (un*2 + wh)*512 + l8);
      __builtin_amdgcn_sched_barrier(0);
      f32x4 c0 = {0.f,0.f,0.f,0.f}, c1 = {0.f,0.f,0.f,0.f}, c2 = {0.f,0.f,0.f,0.f};
      c0 = __builtin_amdgcn_mfma_f32_16x16x32_bf16(ax1[0], s0, c0, 0,0,0);
      c1 = __builtin_amdgcn_mfma_f32_16x16x32_bf16(ax1[1], s0, c1, 0,0,0);
      c2 = __builtin_amdgcn_mfma_f32_16x16x32_bf16(ax1[2], s0, c2, 0,0,0);
      const f32x4 t0 = *(const f32x4*)&m1t[u][0][eq];
      const f32x4 t1 = *(const f32x4*)&m1t[u][1][eq];
      const f32x4 t2 = *(const f32x4*)&m1t[u][2][eq];
#pragma unroll
      for (int r = 0; r < 4; ++r) gg_p[r] += t0[r]*c0[r] + t1[r]*c1[r] + t2[r]*c2[r];
      u = un; s0 = ns;
    }
  }
  // T012: gv, v = uw + 2j, v < 32 (16 iters, K=32), A = m0
  {
    int v = uw;
    short8 s0 = *(const short8*)(b012 + (v*2 + wh)*512 + l8);
    for (int j = 0; j < 16; ++j) {
      const int vn = (j < 15) ? v + 2 : v;
      short8 ns = *(const short8*)(b012 + (vn*2 + wh)*512 + l8);
      __builtin_amdgcn_sched_barrier(0);
      f32x4 c = {0.f,0.f,0.f,0.f};
      c = __builtin_amdgcn_mfma_f32_16x16x32_bf16(am0, s0, c, 0,0,0);
#pragma unroll
      for (int m = 0; m < 3; ++m) {
        const f32x4 t = *(const f32x4*)&x1t[v][m][eq];
#pragma unroll
        for (int r = 0; r < 4; ++r) gv_p[m][r] += t[r]*c[r];
      }
      v = vn; s0 = ns;
    }
  }
  // T102: gv, u = uw + 2j, u < 32 (16 iters, K=64)
  {
    int u = uw;
    const short* p = b102 + (u*2 + wh)*1024 + l8;
    short8 ba = *(const short8*)p, bb = *(const short8*)(p + 512);
    for (int j = 0; j < 16; ++j) {
      const int un = (j < 15) ? u + 2 : u;
      const short* np = b102 + (un*2 + wh)*1024 + l8;
      short8 na = *(const short8*)np, nb = *(const short8*)(np + 512);
      __builtin_amdgcn_sched_barrier(0);
      f32x4 c = {0.f,0.f,0.f,0.f};
      c = __builtin_amdgcn_mfma_f32_16x16x32_bf16(ax0a, ba, c, 0,0,0);
      c = __builtin_amdgcn_mfma_f32_16x16x32_bf16(ax0c, bb, c, 0,0,0);
#pragma unroll
      for (int m = 0; m < 3; ++m) {
        const f32x4 t = *(const f32x4*)&m1t[u][m][eq];
#pragma unroll
        for (int r = 0; r < 4; ++r) gv_p[m][r] += t[r]*c[r];
      }
      u = un; ba = na; bb = nb;
    }
  }

#pragma unroll
  for (int r = 0; r < 4; ++r) {
    atomicAdd(&gs_s[eq + r][nn], gs_p[r]);
    atomicAdd(&gg_s[eq + r][wh*16 + nn], gg_p[r]);
#pragma unroll
    for (int m = 0; m < 3; ++m)
      atomicAdd(&gv_s[eq + r][(wh*16 + nn)*3 + m], gv_p[m][r]);
  }
  __syncthreads();

  // epilogue + fused masked canonical pooling
  for (int i = tid; i < 16*112; i += 256) {
    int n = i / 112, f = i - n*112;
    float o;
    if (f < 16) {
      o = cst_sig / (1.f + expf(-PW_G01f * gs_s[n][f]));
    } else {
      int j = f - 16; int w = j/3;
      float gate = cst_tanh * tanhf(PW_G01f * gg_s[n][w]);
      o = gate * (PW_G2f * INV_SQRT3f) * gv_s[n][j];
    }
    const int gn = n0 + n;
    xg[gn*112 + f] = o;
    if (z[gn] > 1) {
      const int c = canonical[gn];
      atomicAdd(&sums[c*112 + f], o);
      if (f == 0) atomicAdd(&cnt[c], 1.f);
    }
  }
}

// ---------------- K5: quadratic head -> th (R8 version) --------------------
__global__ __launch_bounds__(256) void k5_thead(const float* __restrict__ sums,
                                                const float* __restrict__ cnt,
                                                const float* __restrict__ Wa,
                                                const float* __restrict__ Wb,
                                                const float* __restrict__ Wc,
                                                const float* __restrict__ wdt,
                                                float* __restrict__ th) {
  __shared__ float xh_s[8][112];
  __shared__ float cm_s[8][1024];
  __shared__ float red[256];
  const int tid = threadIdx.x;
  const int n0 = blockIdx.x * 8;
  for (int i = tid; i < 8*112; i += 256) {
    int n = i / 112, j = i - n*112;
    float cv = fmaxf(cnt[n0+n], 1.f);
    xh_s[n][j] = sums[(n0+n)*112 + j] / cv;
  }
  __syncthreads();
  for (int i = tid; i < 8192; i += 256) {
    int n = i >> 10, uv = i & 1023, u = uv >> 5, v = uv & 31;
    const float* hh = xh_s[n] + 16;
    cm_s[n][uv] = hh[u*3]*hh[v*3] + hh[u*3+1]*hh[v*3+1] + hh[u*3+2]*hh[v*3+2];
  }
  __syncthreads();
  {                                     // Wd dot split across 2 threads
    const int hs = tid >> 7, p = tid & 127;
    const int n = p >> 4, k = p & 15;
    float wd = 0.f;
    const float* cp = cm_s[n] + hs*512;
    const float* wp = wdt + k*1024 + hs*512;
#pragma unroll 4
    for (int uv = 0; uv < 512; uv += 4) {
      const f32x4 a = *(const f32x4*)&cp[uv];
      const f32x4 bq = *(const f32x4*)&wp[uv];
      wd += a[0]*bq[0] + a[1]*bq[1] + a[2]*bq[2] + a[3]*bq[3];
    }
    red[tid] = wd;
  }
  __syncthreads();
  if (tid < 128) {
    int n = tid >> 4, k = tid & 15;
    float sA = 0.f;
    for (int v = 0; v < 16; ++v) sA += Wa[k*16+v]*xh_s[n][v];
    float wd = red[tid] + red[tid + 128];
    th[(n0+n)*112 + k] = PW_H0f*(xh_s[n][k]*sA + INV_SQRT3f*wd);
  }
  {
    int n = tid >> 5, j = tid & 31;
    float wb = 0.f, wc = 0.f;
    for (int u = 0; u < 16; ++u) wb += Wb[u*32+j]*xh_s[n][u];
    for (int v = 0; v < 16; ++v) wc += Wc[j*16+v]*xh_s[n][v];
    float cb = PW_H1f * INV_SQRT3f * (wb + wc);
    const float* hh = xh_s[n] + 16;
    float* o = th + (n0+n)*112 + 16 + j*3;
    o[0] = cb*hh[j*3]; o[1] = cb*hh[j*3+1]; o[2] = cb*hh[j*3+2];
  }
}

// ---------------- K6: select + output linear (transposed W reads) ----------
__global__ __launch_bounds__(256) void k6_out(const float* __restrict__ xg,
                                              const float* __restrict__ th,
                                              const int* __restrict__ z,
                                              const int* __restrict__ canonical,
                                              const float* __restrict__ wl0t,
                                              const float* __restrict__ wl1t,
                                              float* __restrict__ out) {
  int idx = blockIdx.x * 256 + threadIdx.x;
  int n = idx / 112, j = idx - n*112;
  const float* yr = (z[n] > 1) ? (th + canonical[n]*112) : (xg + n*112);
  float o = 0.f;
  if (j < 16) {
    const float* wp = wl0t + j*16;
#pragma unroll 4
    for (int v = 0; v < 16; ++v) o += yr[v]*wp[v];
    o *= 0.25f;
  } else {
    int jj = j - 16, w = jj / 3, m = jj - w*3;
    const float* wp = wl1t + w*32;
#pragma unroll 4
    for (int u = 0; u < 32; ++u) o += yr[16 + u*3 + m]*wp[u];
    o *= RSQRT32f;
  }
  out[idx] = o;
}

// ---------------- host: replicate numpy's trapz normalization constants ----
namespace {
struct Csts {
  float silu, sig, tanh_;
  Csts() {
    const int NPT = 200001;
    const double a = -12.0, b = 12.0;
    const double dx = (b - a) / (NPT - 1);
    double s1 = 0.0, s2 = 0.0, s3 = 0.0;
    for (int i = 0; i < NPT; ++i) {
      double xv = a + dx*i;
      double pdf = std::exp(-0.5*xv*xv) / std::sqrt(2.0*M_PI);
      double sg = 1.0 / (1.0 + std::exp(-xv));
      double f1 = xv*sg, f2 = sg, f3 = std::tanh(xv);
      double wg = (i == 0 || i == NPT-1) ? 0.5 : 1.0;
      s1 += wg*f1*f1*pdf; s2 += wg*f2*f2*pdf; s3 += wg*f3*f3*pdf;
    }
    silu  = (float)(1.0/std::sqrt(s1*dx));
    sig   = (float)(1.0/std::sqrt(s2*dx));
    tanh_ = (float)(1.0/std::sqrt(s3*dx));
  }
};
}  // namespace

extern "C" void kernel_launch(void* const* d_in, const int* in_sizes, int n_in,
                              void* d_out, int out_size, void* d_ws, size_t ws_size,
                              hipStream_t stream) {
  const float* x     = (const float*)d_in[0];
  const float* ea    = (const float*)d_in[1];
  const float* W1    = (const float*)d_in[2];
  const float* W2    = (const float*)d_in[3];
  const float* Wg000 = (const float*)d_in[4];
  const float* Wg110 = (const float*)d_in[5];
  const float* Wg001 = (const float*)d_in[6];
  const float* Wg111 = (const float*)d_in[7];
  const float* Wg012 = (const float*)d_in[8];
  const float* Wg102 = (const float*)d_in[9];
  const float* Wa    = (const float*)d_in[10];
  const float* Wb    = (const float*)d_in[11];
  const float* Wc    = (const float*)d_in[12];
  const float* Wd    = (const float*)d_in[13];
  const float* WL0   = (const float*)d_in[14];
  const float* WL1   = (const float*)d_in[15];
  const int* ei      = (const int*)d_in[16];
  const int* z       = (const int*)d_in[17];
  const int* canonical = (const int*)d_in[18];
  float* out = (float*)d_out;

  // workspace layout (floats); no trailing backslashes in comments (R9 bug)
  float* ws   = (float*)d_ws;
  short* hbf  = (short*)ws;            // 3,072,000 bf16
  short* w2s  = (short*)(ws + 1536000);//   589,824 bf16 (swizzled fragments)
  short* bt   = (short*)(ws + 1831000);//   196,608 bf16 gate tables (swizzled)
  float* nm   = ws + 1930000;          //   896,000 (zeroed, contiguous block)
  float* sums = ws + 2826000;          //   896,000 (zeroed)
  float* cnt  = ws + 3722000;          //     8,000 (zeroed)
  float* xg   = ws + 3730000;          //   896,000
  float* th   = ws + 4626000;          //   896,000
  float* wdt  = ws + 5522000;          //    16,384
  float* wl0t = ws + 5538384;          //       256
  float* wl1t = ws + 5538640;          //     1,024  -> total 5,539,664 floats

  static const Csts C;                 // host-only; safe under graph capture

  k_prep<<<6171, 256, 0, stream>>>(W2, Wg000, Wg110, Wg001, Wg111, Wg012,
                                   Wg102, Wd, WL0, WL1, ea, W1,
                                   w2s, bt, wdt, wl0t, wl1t, hbf, nm, C.silu);
  k2_edge_msg<<<750, 256, 0, stream>>>(x, ea, w2s, hbf, ei, nm);
  k3_gate<<<500, 256, 0, stream>>>(x, nm, bt, z, canonical, xg, sums, cnt,
                                   C.sig, C.tanh_);
  k5_thead<<<1000, 256, 0, stream>>>(sums, cnt, Wa, Wb, Wc, wdt, th);
  k6_out<<<3500, 256, 0, stream>>>(xg, th, z, canonical, wl0t, wl1t, out);
}